// Round 8
// baseline (8221.130 us; speedup 1.0000x reference)
//
#include <hip/hip_runtime.h>

#define N 100
#define NN (N * N)
#define HINF 1e9f

typedef float vf128 __attribute__((ext_vector_type(128)));

// read element idx (0..127) of a value distributed as lane-owned pairs (a: idx<64, b: idx>=64)
__device__ __forceinline__ int rl2_i(int a, int b, int idx) {
    int lo = __builtin_amdgcn_readlane(a, idx & 63);
    int hi = __builtin_amdgcn_readlane(b, idx & 63);
    return (idx < 64) ? lo : hi;
}
__device__ __forceinline__ float rl2_f(float a, float b, int idx) {
    int lo = __builtin_amdgcn_readlane(__float_as_int(a), idx & 63);
    int hi = __builtin_amdgcn_readlane(__float_as_int(b), idx & 63);
    return __int_as_float((idx < 64) ? lo : hi);
}

// full-wave64 min via DPP (VALU-only), broadcast via readlane 63
__device__ __forceinline__ float wave_min_bcast(float x) {
    int v = __float_as_int(x);
#define STEP(ctrl)                                                                  \
    do {                                                                            \
        int t = __builtin_amdgcn_update_dpp(v, v, (ctrl), 0xF, 0xF, false);         \
        v = __float_as_int(fminf(__int_as_float(v), __int_as_float(t)));            \
    } while (0)
    STEP(0x111); /* row_shr:1  */
    STEP(0x112); /* row_shr:2  */
    STEP(0x114); /* row_shr:4  */
    STEP(0x118); /* row_shr:8  */
    STEP(0x142); /* row_bcast:15 */
    STEP(0x143); /* row_bcast:31 -> lane 63 has full min */
#undef STEP
    return __int_as_float(__builtin_amdgcn_readlane(v, 63));
}

// One block = one wave per batch element. The ENTIRE cost matrix lives in
// VGPRs (two 128-wide vectors per lane: ca[i]=cost[i][lane], cb[i]=cost[i][lane+64]);
// the wave-uniform row index makes the dynamic extract a v_movrels (M0) read,
// removing the ~150-cycle LDS hop from the serial augmenting-path chain.
__global__ __launch_bounds__(64, 1) void hungarian_kernel(
    const float* __restrict__ cost_all,
    const int* __restrict__ num_objects,
    float* __restrict__ out_mask,
    float* __restrict__ out_pred)
{
    __shared__ int p_sh[N];

    const int b    = blockIdx.x;
    const int lane = threadIdx.x;
    const float* cost = cost_all + (size_t)b * NN;
    const int nobj = num_objects[b];

    const bool hb = (lane + 64) < N;   // lane owns col B = lane+64 (valid if <100)

    // ---- stage cost into registers (coalesced row reads), zero padding rows ----
    vf128 ca, cb;
#pragma unroll
    for (int i = 0; i < N; ++i) {
        ca[i] = (i < nobj) ? cost[i * N + lane] : 0.0f;
        cb[i] = (hb && i < nobj) ? cost[i * N + 64 + lane] : 0.0f;
    }
#pragma unroll
    for (int i = N; i < 128; ++i) { ca[i] = 0.0f; cb[i] = 0.0f; }

    const int ja = lane;        // owned col A (0..63)
    const int jb = lane + 64;   // owned col B (64..127; >=100 invalid)

    // distributed state: lane owns cols {ja, jb} and rows {lane, lane+64}
    float u_a = 0.f, u_b = 0.f;    // row potentials
    float v_a = 0.f, v_b = 0.f;    // col potentials
    int   p_a = -1,  p_b = -1;     // col -> matched row

    for (int r = 0; r < N; ++r) {
        float minv_a = HINF, minv_b = HINF;
        int   way_a = -1, way_b = -1;
        bool  used_a = false, used_b = !hb;   // invalid cols permanently "used"
        bool  intree_a = false, intree_b = false;
        int   j0 = -1;
        int   jfin = -1;

        for (int it = 0; it < 128; ++it) {
            int i0;
            if (j0 < 0) {
                i0 = r;
            } else {
                const int pj0 = rl2_i(p_a, p_b, j0);
                if (pj0 < 0) { jfin = j0; break; }   // reached free column
                i0 = pj0;
            }

            // row i0 joins the tree; u[i0] is read before this iter's update
            if (lane == (i0 & 63)) { if (i0 < 64) intree_a = true; else intree_b = true; }
            const float ui0 = rl2_f(u_a, u_b, i0);
            const int   iu  = __builtin_amdgcn_readfirstlane(i0);  // uniform index
            const float c_a = ca[iu];   // v_movrels (M0-indexed VGPR read)
            const float c_b = cb[iu];

            const float cur_a = (c_a - ui0) - v_a;
            if (!used_a && cur_a < minv_a) { minv_a = cur_a; way_a = j0; }
            const float cur_b = (c_b - ui0) - v_b;
            if (!used_b && cur_b < minv_b) { minv_b = cur_b; way_b = j0; }

            const float va = used_a ? HINF : minv_a;
            const float vb = used_b ? HINF : minv_b;
            const float delta = wave_min_bcast(fminf(va, vb));

            // first index attaining the min: A-cols (0..63) always precede B-cols
            const unsigned long long ba = __ballot(va == delta);
            const unsigned long long bb = __ballot(vb == delta);
            const int j1 = (ba != 0ull) ? (__ffsll((long long)ba) - 1)
                                        : (64 + __ffsll((long long)bb) - 1);

            // dual updates: identical per-element add sequence to the reference
            if (intree_a) u_a += delta;
            if (intree_b) u_b += delta;
            if (used_a) v_a -= delta; else minv_a -= delta;
            if (used_b) v_b -= delta; else minv_b -= delta;
            used_a |= (j1 == ja);
            used_b |= (j1 == jb);
            j0 = j1;
        }

        // ---- augment: walk predecessor chain, flipping matches (register-only) ----
        int jj = jfin;
        for (int g = 0; g < N + 4 && jj >= 0; ++g) {
            const int w  = rl2_i(way_a, way_b, jj);
            const int pi = (w < 0) ? r : rl2_i(p_a, p_b, w);
            if (lane == (jj & 63)) {
                if (jj < 64) p_a = pi; else p_b = pi;
            }
            jj = w;
        }
    }

    // ---- outputs ----
    p_sh[lane] = p_a;
    if (hb) p_sh[jb] = p_b;
    __syncthreads();

    float* mask = out_mask + (size_t)b * NN;
    for (int f = lane * 4; f < NN; f += 256) {
        float e[4];
#pragma unroll
        for (int k = 0; k < 4; ++k) {
            const int idx = f + k;
            const int i = idx / N;
            const int j = idx - i * N;
            e[k] = (p_sh[j] == i && i < nobj) ? 1.0f : 0.0f;
        }
        *reinterpret_cast<float4*>(mask + f) = make_float4(e[0], e[1], e[2], e[3]);
    }
    for (int j = lane; j < N; j += 64) {
        out_pred[(size_t)b * N + j] = (p_sh[j] < nobj) ? 1.0f : 0.0f;
    }
}

extern "C" void kernel_launch(void* const* d_in, const int* in_sizes, int n_in,
                              void* d_out, int out_size, void* d_ws, size_t ws_size,
                              hipStream_t stream) {
    const float* cost = (const float*)d_in[0];
    const int*   nobj = (const int*)d_in[1];
    float*       out  = (float*)d_out;
    const int B = in_sizes[1];                     // 256
    float* out_mask = out;                         // [B,100,100]
    float* out_pred = out + (size_t)B * N * N;     // [B,100,1]
    hipLaunchKernelGGL(hungarian_kernel, dim3(B), dim3(64), 0, stream,
                       cost, nobj, out_mask, out_pred);
}

// Round 9
// 1636.759 us; speedup vs baseline: 5.0228x; 5.0228x over previous
//
#include <hip/hip_runtime.h>

#define N 100
#define NN (N * N)
#define HINF 1e9f

// read element idx (0..127) of a value distributed as lane-owned pairs (a: idx<64, b: idx>=64)
__device__ __forceinline__ int rl2_i(int a, int b, int idx) {
    int lo = __builtin_amdgcn_readlane(a, idx & 63);
    int hi = __builtin_amdgcn_readlane(b, idx & 63);
    return (idx < 64) ? lo : hi;
}
__device__ __forceinline__ float rl2_f(float a, float b, int idx) {
    int lo = __builtin_amdgcn_readlane(__float_as_int(a), idx & 63);
    int hi = __builtin_amdgcn_readlane(__float_as_int(b), idx & 63);
    return __int_as_float((idx < 64) ? lo : hi);
}

// full-wave64 min via DPP (VALU-only), broadcast via readlane 63
__device__ __forceinline__ float wave_min_bcast(float x) {
    int v = __float_as_int(x);
#define STEP(ctrl)                                                                  \
    do {                                                                            \
        int t = __builtin_amdgcn_update_dpp(v, v, (ctrl), 0xF, 0xF, false);         \
        v = __float_as_int(fminf(__int_as_float(v), __int_as_float(t)));            \
    } while (0)
    STEP(0x111); /* row_shr:1  */
    STEP(0x112); /* row_shr:2  */
    STEP(0x114); /* row_shr:4  */
    STEP(0x118); /* row_shr:8  */
    STEP(0x142); /* row_bcast:15 */
    STEP(0x143); /* row_bcast:31 -> lane 63 has full min */
#undef STEP
    return __int_as_float(__builtin_amdgcn_readlane(v, 63));
}

// One block = one wave (64 lanes) per batch element. Algorithm state in
// registers; cost matrix in LDS. The next tree-row's ds_read is issued the
// moment its index is known (clamped, speculative on break iterations), and
// ALL dual-update bookkeeping executes in the LDS shadow between issue and
// consume — in-order issue then overlaps ~60cy of VALU with the LDS latency.
__global__ __launch_bounds__(64) void hungarian_kernel(
    const float* __restrict__ cost_all,
    const int* __restrict__ num_objects,
    float* __restrict__ out_mask,
    float* __restrict__ out_pred)
{
    __shared__ float c_lds[NN + 32];  // +pad so base+64 reads never go OOB
    __shared__ int   p_sh[N];

    const int b    = blockIdx.x;
    const int lane = threadIdx.x;
    const float* cost = cost_all + (size_t)b * NN;
    const int nobj = num_objects[b];

    // ---- stage cost into LDS, zeroing padding rows (i >= nobj) ----
    for (int f = lane * 4; f < NN; f += 256) {
        float4 vv = *reinterpret_cast<const float4*>(cost + f);
        float e0 = ((f + 0) / N < nobj) ? vv.x : 0.0f;
        float e1 = ((f + 1) / N < nobj) ? vv.y : 0.0f;
        float e2 = ((f + 2) / N < nobj) ? vv.z : 0.0f;
        float e3 = ((f + 3) / N < nobj) ? vv.w : 0.0f;
        *reinterpret_cast<float4*>(c_lds + f) = make_float4(e0, e1, e2, e3);
    }
    if (lane < 32) c_lds[NN + lane] = 0.0f;
    __syncthreads();  // once; staging complete

    const int  ja    = lane;       // owned col A (0..63)
    const int  jb    = lane + 64;  // owned col B (64..127; >=100 invalid)
    const bool has_b = (jb < N);
    const float* crow = c_lds + lane;   // per-lane column base

    // distributed state: lane owns cols {ja, jb} and rows {lane, lane+64}
    float u_a = 0.f, u_b = 0.f;    // row potentials
    float v_a = 0.f, v_b = 0.f;    // col potentials
    int   p_a = -1,  p_b = -1;     // col -> matched row

    for (int r = 0; r < N; ++r) {
        float minv_a = HINF, minv_b = HINF;
        int   way_a = -1, way_b = -1;
        bool  used_a = false, used_b = !has_b;  // invalid cols permanently "used"
        bool  intree_a = false, intree_b = false;

        // ---- prologue of rotated loop: pending row = r ----
        int   i0 = r;
        int   j0 = -1;                 // column via which pending row was reached
        if (lane == (i0 & 63)) { if (i0 < 64) intree_a = true; else intree_b = true; }
        float ui0 = rl2_f(u_a, u_b, i0);
        float c_a = crow[i0 * N];      // LDS reads in flight into first iteration
        float c_b = crow[i0 * N + 64];
        int   jfin = -1;

        for (int it = 0; it < 128; ++it) {
            // consume pending row (waits lgkm here)
            const float cur_a = (c_a - ui0) - v_a;
            if (!used_a && cur_a < minv_a) { minv_a = cur_a; way_a = j0; }
            const float cur_b = (c_b - ui0) - v_b;
            if (!used_b && cur_b < minv_b) { minv_b = cur_b; way_b = j0; }

            const float va = used_a ? HINF : minv_a;
            const float vb = used_b ? HINF : minv_b;
            const float delta = wave_min_bcast(fminf(va, vb));

            // first index attaining the min: A-cols (0..63) always precede B-cols
            const unsigned long long ba = __ballot(va == delta);
            const unsigned long long bb = __ballot(vb == delta);
            const int j1 = (ba != 0ull) ? (__ffsll((long long)ba) - 1)
                                        : (64 + __ffsll((long long)bb) - 1);
            const int pj1 = rl2_i(p_a, p_b, j1);   // next row (or -1)

            // ---- PREFETCH next row's cost NOW (cost is constant; clamp -1) ----
            const int inext = (pj1 < 0) ? 0 : pj1;
            c_a = crow[inext * N];
            c_b = crow[inext * N + 64];

            // dual updates (exact reference order per element), in LDS shadow
            if (intree_a) u_a += delta;
            if (intree_b) u_b += delta;
            if (used_a) v_a -= delta;
            if (used_b) v_b -= delta;
            minv_a -= delta;   // unconditional: used lanes' minv is never consumed
            minv_b -= delta;
            used_a |= (j1 == ja);
            used_b |= (j1 == jb);

            if (pj1 < 0) { jfin = j1; break; }     // reached a free column

            // bookkeeping for next pending row (off critical path).
            // row pj1 was NOT in the tree this iteration, so u[pj1] is unchanged
            // by the update above -> reading it now is bit-identical to reference.
            i0 = pj1;
            j0 = j1;
            if (lane == (i0 & 63)) { if (i0 < 64) intree_a = true; else intree_b = true; }
            ui0 = rl2_f(u_a, u_b, i0);
        }

        // ---- augment: walk predecessor chain, flipping matches (register-only) ----
        int jj = jfin;
        for (int g = 0; g < N + 4 && jj >= 0; ++g) {
            const int w  = rl2_i(way_a, way_b, jj);
            const int pi = (w < 0) ? r : rl2_i(p_a, p_b, w);
            if (lane == (jj & 63)) {
                if (jj < 64) p_a = pi; else p_b = pi;
            }
            jj = w;
        }
    }

    // ---- outputs ----
    p_sh[lane] = p_a;
    if (has_b) p_sh[jb] = p_b;
    __syncthreads();

    float* mask = out_mask + (size_t)b * NN;
    for (int f = lane * 4; f < NN; f += 256) {
        float e[4];
#pragma unroll
        for (int k = 0; k < 4; ++k) {
            const int idx = f + k;
            const int i = idx / N;
            const int j = idx - i * N;
            e[k] = (p_sh[j] == i && i < nobj) ? 1.0f : 0.0f;
        }
        *reinterpret_cast<float4*>(mask + f) = make_float4(e[0], e[1], e[2], e[3]);
    }
    for (int j = lane; j < N; j += 64) {
        out_pred[(size_t)b * N + j] = (p_sh[j] < nobj) ? 1.0f : 0.0f;
    }
}

extern "C" void kernel_launch(void* const* d_in, const int* in_sizes, int n_in,
                              void* d_out, int out_size, void* d_ws, size_t ws_size,
                              hipStream_t stream) {
    const float* cost = (const float*)d_in[0];
    const int*   nobj = (const int*)d_in[1];
    float*       out  = (float*)d_out;
    const int B = in_sizes[1];                     // 256
    float* out_mask = out;                         // [B,100,100]
    float* out_pred = out + (size_t)B * N * N;     // [B,100,1]
    hipLaunchKernelGGL(hungarian_kernel, dim3(B), dim3(64), 0, stream,
                       cost, nobj, out_mask, out_pred);
}